// Round 4
// baseline (313.554 us; speedup 1.0000x reference)
//
#include <hip/hip_runtime.h>

#define IN_DIM 128
#define HC     256      // H*C
#define CCH    64
#define NH     4
#define NEG    0.2f

typedef __attribute__((ext_vector_type(4))) float f32x4;
typedef __attribute__((ext_vector_type(8))) short short8;

static __device__ __forceinline__ unsigned short f2bf(float f) {
  unsigned int u = __float_as_uint(f);
  u = (u + 0x7fffu + ((u >> 16) & 1u)) >> 16;   // RNE
  return (unsigned short)u;
}
static __device__ __forceinline__ float bf2f(unsigned short b) {
  return __uint_as_float(((unsigned int)b) << 16);
}

// ---------------- K0: per-relation attention term ----------------
__global__ void rel_attn_k(const float* __restrict__ rel_emb,
                           const float* __restrict__ W_edge,
                           const float* __restrict__ att_edge,
                           float* __restrict__ a_rel) {
  int r = blockIdx.x;
  int lane = threadIdx.x;  // 64 threads
  __shared__ float re[IN_DIM];
  re[lane]      = rel_emb[r * IN_DIM + lane];
  re[lane + 64] = rel_emb[r * IN_DIM + 64 + lane];
  __syncthreads();
  float p[NH];
#pragma unroll
  for (int h = 0; h < NH; ++h) {
    const float* wrow = W_edge + (size_t)(h * CCH + lane) * IN_DIM;
    float d = 0.f;
#pragma unroll
    for (int k = 0; k < IN_DIM; ++k) d += re[k] * wrow[k];
    p[h] = d * att_edge[h * CCH + lane];
  }
#pragma unroll
  for (int off = 32; off; off >>= 1) {
#pragma unroll
    for (int h = 0; h < NH; ++h) p[h] += __shfl_down(p[h], off);
  }
  if (lane == 0) {
#pragma unroll
    for (int h = 0; h < NH; ++h) a_rel[r * NH + h] = p[h];
  }
}

// ---------------- K1: MFMA bf16 GEMM, x staged ONCE, heads looped in-block ----------------
// BM=128 rows per block; for h in 0..3: stage W-slice, mfma, epilogue.
__global__ __launch_bounds__(256) void gemm_mfma_k(
    const float* __restrict__ x, const float* __restrict__ W,
    const float* __restrict__ att_src, const float* __restrict__ att_dst,
    unsigned short* __restrict__ xpb, float* __restrict__ a_srcv,
    float* __restrict__ a_dstv, int Nn) {
  __shared__ unsigned short Asm[128][136];  // 34.8 KB
  __shared__ unsigned short Bsm[64][136];   // 17.4 KB
  const int tid = threadIdx.x;
  const int bm = blockIdx.x * 128;

  // stage A (x rows bm..bm+127, f32 -> bf16), once
  {
    int row = tid >> 1, ch = (tid & 1) * 64;
    int gm = bm + row;
    if (gm < Nn) {
      const float* xr = x + (size_t)gm * IN_DIM + ch;
#pragma unroll
      for (int i = 0; i < 64; i += 8) {
        float4 a = *(const float4*)(xr + i);
        float4 b = *(const float4*)(xr + i + 4);
        ushort4 u0, u1;
        u0.x = f2bf(a.x); u0.y = f2bf(a.y); u0.z = f2bf(a.z); u0.w = f2bf(a.w);
        u1.x = f2bf(b.x); u1.y = f2bf(b.y); u1.z = f2bf(b.z); u1.w = f2bf(b.w);
        *(ushort4*)&Asm[row][ch + i]     = u0;
        *(ushort4*)&Asm[row][ch + i + 4] = u1;
      }
    } else {
      ushort4 zz = {0, 0, 0, 0};
#pragma unroll
      for (int i = 0; i < 64; i += 4) *(ushort4*)&Asm[row][ch + i] = zz;
    }
  }

  const int wv = tid >> 6, lane = tid & 63;
  const int lr = lane & 15, lk = lane >> 4;

  for (int h = 0; h < NH; ++h) {
    __syncthreads();   // prev head's Bsm reads done (and h=0: A staged)
    if (tid < 128) {
      int row = tid >> 1, ch = (tid & 1) * 64;
      const float* wr = W + (size_t)(h * CCH + row) * IN_DIM + ch;
#pragma unroll
      for (int i = 0; i < 64; i += 8) {
        float4 a = *(const float4*)(wr + i);
        float4 b = *(const float4*)(wr + i + 4);
        ushort4 u0, u1;
        u0.x = f2bf(a.x); u0.y = f2bf(a.y); u0.z = f2bf(a.z); u0.w = f2bf(a.w);
        u1.x = f2bf(b.x); u1.y = f2bf(b.y); u1.z = f2bf(b.z); u1.w = f2bf(b.w);
        *(ushort4*)&Bsm[row][ch + i]     = u0;
        *(ushort4*)&Bsm[row][ch + i + 4] = u1;
      }
    }
    __syncthreads();

    f32x4 acc[2][4] = {};
#pragma unroll
    for (int kk = 0; kk < 4; ++kk) {
      const int ko = kk * 32 + lk * 8;
      short8 af0 = *(const short8*)&Asm[wv * 32 + lr][ko];
      short8 af1 = *(const short8*)&Asm[wv * 32 + 16 + lr][ko];
      short8 bf0 = *(const short8*)&Bsm[lr][ko];
      short8 bf1 = *(const short8*)&Bsm[16 + lr][ko];
      short8 bf2v = *(const short8*)&Bsm[32 + lr][ko];
      short8 bf3 = *(const short8*)&Bsm[48 + lr][ko];
      acc[0][0] = __builtin_amdgcn_mfma_f32_16x16x32_bf16(af0, bf0, acc[0][0], 0, 0, 0);
      acc[0][1] = __builtin_amdgcn_mfma_f32_16x16x32_bf16(af0, bf1, acc[0][1], 0, 0, 0);
      acc[0][2] = __builtin_amdgcn_mfma_f32_16x16x32_bf16(af0, bf2v, acc[0][2], 0, 0, 0);
      acc[0][3] = __builtin_amdgcn_mfma_f32_16x16x32_bf16(af0, bf3, acc[0][3], 0, 0, 0);
      acc[1][0] = __builtin_amdgcn_mfma_f32_16x16x32_bf16(af1, bf0, acc[1][0], 0, 0, 0);
      acc[1][1] = __builtin_amdgcn_mfma_f32_16x16x32_bf16(af1, bf1, acc[1][1], 0, 0, 0);
      acc[1][2] = __builtin_amdgcn_mfma_f32_16x16x32_bf16(af1, bf2v, acc[1][2], 0, 0, 0);
      acc[1][3] = __builtin_amdgcn_mfma_f32_16x16x32_bf16(af1, bf3, acc[1][3], 0, 0, 0);
    }

    // epilogue head h
    float as4[4], ad4[4];
#pragma unroll
    for (int ni = 0; ni < 4; ++ni) {
      as4[ni] = att_src[h * CCH + ni * 16 + lr];
      ad4[ni] = att_dst[h * CCH + ni * 16 + lr];
    }
#pragma unroll
    for (int mi = 0; mi < 2; ++mi) {
#pragma unroll
      for (int r = 0; r < 4; ++r) {
        int gm = bm + wv * 32 + mi * 16 + lk * 4 + r;
        bool ok = (gm < Nn);
        if (ok) {
#pragma unroll
          for (int ni = 0; ni < 4; ++ni)
            xpb[(size_t)gm * HC + h * CCH + ni * 16 + lr] = f2bf(acc[mi][ni][r]);
        }
        float ps = 0.f, pd = 0.f;
#pragma unroll
        for (int ni = 0; ni < 4; ++ni) {
          ps += acc[mi][ni][r] * as4[ni];
          pd += acc[mi][ni][r] * ad4[ni];
        }
        ps += __shfl_xor(ps, 1); pd += __shfl_xor(pd, 1);
        ps += __shfl_xor(ps, 2); pd += __shfl_xor(pd, 2);
        ps += __shfl_xor(ps, 4); pd += __shfl_xor(pd, 4);
        ps += __shfl_xor(ps, 8); pd += __shfl_xor(pd, 8);
        if (lr == 0 && ok) {
          a_srcv[(size_t)gm * NH + h] = ps;
          a_dstv[(size_t)gm * NH + h] = pd;
        }
      }
    }
  }
}

// ---------------- K2: histogram of dst ----------------
__global__ void hist_k(const int* __restrict__ dst, int* __restrict__ counts, int E) {
  int e = blockIdx.x * 256 + threadIdx.x;
  if (e < E) atomicAdd(&counts[dst[e]], 1);
}

// ---------------- K3: single-block exclusive scan ----------------
__global__ __launch_bounds__(1024) void scan1_k(const int* __restrict__ counts,
                                                int* __restrict__ offsets,
                                                int* __restrict__ cursor, int n, int E) {
  __shared__ int ts[1024];
  int tid = threadIdx.x;
  int per = (n + 1023) >> 10;
  int i0 = tid * per;
  int iend = i0 + per; if (iend > n) iend = n;
  int s = 0;
  for (int i = i0; i < iend; ++i) s += counts[i];
  ts[tid] = s;
  __syncthreads();
  for (int off = 1; off < 1024; off <<= 1) {
    int t = (tid >= off) ? ts[tid - off] : 0;
    __syncthreads();
    ts[tid] += t;
    __syncthreads();
  }
  int base = tid ? ts[tid - 1] : 0;
  for (int i = i0; i < iend; ++i) {
    offsets[i] = base;
    cursor[i] = base;
    base += counts[i];
  }
  if (tid == 1023) offsets[n] = E;
}

// ---------------- K4: scatter packed (etype<<26 | src) into dst-sorted order ----------------
__global__ void scatter_k(const int* __restrict__ src, const int* __restrict__ dst,
                          const int* __restrict__ et, int* __restrict__ cursor,
                          unsigned int* __restrict__ packed, int E) {
  int e = blockIdx.x * 256 + threadIdx.x;
  if (e >= E) return;
  int d = dst[e];
  unsigned int pk = ((unsigned int)et[e] << 26) | (unsigned int)src[e];
  int pos = atomicAdd(&cursor[d], 1);
  packed[pos] = pk;
}

// ---------------- K5: one wave per dst: recompute w, aggregate, write ----------------
__global__ void gat_out_k(const int* __restrict__ offsets,
                          const unsigned int* __restrict__ packed,
                          const float* __restrict__ a_srcv, const float* __restrict__ a_dstv,
                          const float* __restrict__ a_rel, int R,
                          const unsigned short* __restrict__ xpb,
                          const float* __restrict__ bias,
                          float* __restrict__ out, int Nn) {
  __shared__ float arl[NH * 64];
  int tid = threadIdx.x;
  if (tid < R * NH) arl[tid] = a_rel[tid];
  __syncthreads();
  int d = blockIdx.x * 4 + (tid >> 6);
  if (d >= Nn) return;
  int lane = tid & 63;
  int h = lane >> 4, c4 = (lane & 15) * 4;
  const int hco = h * CCH + c4;
  int beg = offsets[d], end = offsets[d + 1];
  float ad = a_dstv[(size_t)d * NH + h];
  float z = 0.f, a0 = 0.f, a1 = 0.f, a2 = 0.f, a3 = 0.f;
  int j = beg;
  for (; j + 4 <= end; j += 4) {
    unsigned int pk[4];
#pragma unroll
    for (int q = 0; q < 4; ++q) pk[q] = packed[j + q];
    float w[4]; ushort4 u[4];
#pragma unroll
    for (int q = 0; q < 4; ++q) {
      int s = (int)(pk[q] & 0x03FFFFFFu);
      int t = (int)(pk[q] >> 26);
      float al = a_srcv[(size_t)s * NH + h] + ad + arl[t * NH + h];
      al = fmaxf(al, NEG * al);
      w[q] = __expf(al);
      u[q] = *(const ushort4*)(xpb + (size_t)s * HC + hco);
    }
#pragma unroll
    for (int q = 0; q < 4; ++q) {
      z += w[q];
      a0 += w[q] * bf2f(u[q].x);
      a1 += w[q] * bf2f(u[q].y);
      a2 += w[q] * bf2f(u[q].z);
      a3 += w[q] * bf2f(u[q].w);
    }
  }
  for (; j < end; ++j) {
    unsigned int pk = packed[j];
    int s = (int)(pk & 0x03FFFFFFu);
    int t = (int)(pk >> 26);
    float al = a_srcv[(size_t)s * NH + h] + ad + arl[t * NH + h];
    al = fmaxf(al, NEG * al);
    float w = __expf(al);
    ushort4 u = *(const ushort4*)(xpb + (size_t)s * HC + hco);
    z += w;
    a0 += w * bf2f(u.x);
    a1 += w * bf2f(u.y);
    a2 += w * bf2f(u.z);
    a3 += w * bf2f(u.w);
  }
  float inv = 0.25f / (z + 1e-16f);
  a0 *= inv; a1 *= inv; a2 *= inv; a3 *= inv;
  a0 += __shfl_down(a0, 32); a1 += __shfl_down(a1, 32);
  a2 += __shfl_down(a2, 32); a3 += __shfl_down(a3, 32);
  a0 += __shfl_down(a0, 16); a1 += __shfl_down(a1, 16);
  a2 += __shfl_down(a2, 16); a3 += __shfl_down(a3, 16);
  if (lane < 16) {
    const float4 b4 = *(const float4*)(bias + lane * 4);
    float4 o;
    o.x = a0 + b4.x; o.y = a1 + b4.y; o.z = a2 + b4.z; o.w = a3 + b4.w;
    *(float4*)(out + (size_t)d * CCH + lane * 4) = o;
  }
}

extern "C" void kernel_launch(void* const* d_in, const int* in_sizes, int n_in,
                              void* d_out, int out_size, void* d_ws, size_t ws_size,
                              hipStream_t stream) {
  const float* x        = (const float*)d_in[0];
  const int*   eidx     = (const int*)d_in[1];
  const int*   etype    = (const int*)d_in[2];
  const float* rel_emb  = (const float*)d_in[3];
  const float* W        = (const float*)d_in[4];
  const float* att_src  = (const float*)d_in[5];
  const float* att_dst  = (const float*)d_in[6];
  const float* W_edge   = (const float*)d_in[7];
  const float* att_edge = (const float*)d_in[8];
  const float* bias     = (const float*)d_in[9];
  float* out = (float*)d_out;

  const int Nn = in_sizes[0] / IN_DIM;
  const int E  = in_sizes[1] / 2;
  const int R  = in_sizes[3] / IN_DIM;
  const int* src = eidx;
  const int* dst = eidx + E;

  char* ws = (char*)d_ws;
  size_t off = 0;
  auto alloc = [&](size_t bytes) {
    void* p = ws + off;
    off = (off + bytes + 255) & ~(size_t)255;
    return p;
  };
  unsigned short* xpb = (unsigned short*)alloc((size_t)Nn * HC * 2);
  float* a_srcv = (float*)alloc((size_t)Nn * NH * 4);
  float* a_dstv = (float*)alloc((size_t)Nn * NH * 4);
  float* a_rel  = (float*)alloc((size_t)R * NH * 4);
  int*   counts = (int*)alloc((size_t)Nn * 4);
  int*   offsets= (int*)alloc((size_t)(Nn + 1) * 4);
  int*   cursor = (int*)alloc((size_t)Nn * 4);
  unsigned int* packed = (unsigned int*)alloc((size_t)E * 4);

  hipMemsetAsync(counts, 0, (size_t)Nn * 4, stream);

  hipLaunchKernelGGL(rel_attn_k, dim3(R), dim3(64), 0, stream,
                     rel_emb, W_edge, att_edge, a_rel);
  hipLaunchKernelGGL(gemm_mfma_k, dim3((Nn + 127) / 128), dim3(256), 0, stream,
                     x, W, att_src, att_dst, xpb, a_srcv, a_dstv, Nn);
  hipLaunchKernelGGL(hist_k, dim3((E + 255) / 256), dim3(256), 0, stream, dst, counts, E);
  hipLaunchKernelGGL(scan1_k, dim3(1), dim3(1024), 0, stream, counts, offsets, cursor, Nn, E);
  hipLaunchKernelGGL(scatter_k, dim3((E + 255) / 256), dim3(256), 0, stream,
                     src, dst, etype, cursor, packed, E);
  hipLaunchKernelGGL(gat_out_k, dim3((Nn + 3) / 4), dim3(256), 0, stream,
                     offsets, packed, a_srcv, a_dstv, a_rel, R, xpb, bias, out, Nn);
}

// Round 5
// 219.807 us; speedup vs baseline: 1.4265x; 1.4265x over previous
//
#include <hip/hip_runtime.h>

#define IN_DIM 128
#define HC     256      // H*C
#define CCH    64
#define NH     4
#define NEG    0.2f

typedef __attribute__((ext_vector_type(4))) float f32x4;
typedef __attribute__((ext_vector_type(8))) short short8;

static __device__ __forceinline__ unsigned short f2bf(float f) {
  unsigned int u = __float_as_uint(f);
  u = (u + 0x7fffu + ((u >> 16) & 1u)) >> 16;   // RNE
  return (unsigned short)u;
}
static __device__ __forceinline__ float bf2f(unsigned short b) {
  return __uint_as_float(((unsigned int)b) << 16);
}

// ---------------- K0: per-relation attention term ----------------
__global__ void rel_attn_k(const float* __restrict__ rel_emb,
                           const float* __restrict__ W_edge,
                           const float* __restrict__ att_edge,
                           float* __restrict__ a_rel) {
  int r = blockIdx.x;
  int lane = threadIdx.x;  // 64 threads
  __shared__ float re[IN_DIM];
  re[lane]      = rel_emb[r * IN_DIM + lane];
  re[lane + 64] = rel_emb[r * IN_DIM + 64 + lane];
  __syncthreads();
  float p[NH];
#pragma unroll
  for (int h = 0; h < NH; ++h) {
    const float* wrow = W_edge + (size_t)(h * CCH + lane) * IN_DIM;
    float d = 0.f;
#pragma unroll
    for (int k = 0; k < IN_DIM; ++k) d += re[k] * wrow[k];
    p[h] = d * att_edge[h * CCH + lane];
  }
#pragma unroll
  for (int off = 32; off; off >>= 1) {
#pragma unroll
    for (int h = 0; h < NH; ++h) p[h] += __shfl_down(p[h], off);
  }
  if (lane == 0) {
#pragma unroll
    for (int h = 0; h < NH; ++h) a_rel[r * NH + h] = p[h];
  }
}

// ---------------- K1: MFMA bf16 GEMM, x staged ONCE, heads looped in-block ----------------
__global__ __launch_bounds__(256) void gemm_mfma_k(
    const float* __restrict__ x, const float* __restrict__ W,
    const float* __restrict__ att_src, const float* __restrict__ att_dst,
    unsigned short* __restrict__ xpb, float* __restrict__ a_srcv,
    float* __restrict__ a_dstv, int Nn) {
  __shared__ unsigned short Asm[128][136];  // 34.8 KB
  __shared__ unsigned short Bsm[64][136];   // 17.4 KB
  const int tid = threadIdx.x;
  const int bm = blockIdx.x * 128;

  // stage A (x rows bm..bm+127, f32 -> bf16), once
  {
    int row = tid >> 1, ch = (tid & 1) * 64;
    int gm = bm + row;
    if (gm < Nn) {
      const float* xr = x + (size_t)gm * IN_DIM + ch;
#pragma unroll
      for (int i = 0; i < 64; i += 8) {
        float4 a = *(const float4*)(xr + i);
        float4 b = *(const float4*)(xr + i + 4);
        ushort4 u0, u1;
        u0.x = f2bf(a.x); u0.y = f2bf(a.y); u0.z = f2bf(a.z); u0.w = f2bf(a.w);
        u1.x = f2bf(b.x); u1.y = f2bf(b.y); u1.z = f2bf(b.z); u1.w = f2bf(b.w);
        *(ushort4*)&Asm[row][ch + i]     = u0;
        *(ushort4*)&Asm[row][ch + i + 4] = u1;
      }
    } else {
      ushort4 zz = {0, 0, 0, 0};
#pragma unroll
      for (int i = 0; i < 64; i += 4) *(ushort4*)&Asm[row][ch + i] = zz;
    }
  }

  const int wv = tid >> 6, lane = tid & 63;
  const int lr = lane & 15, lk = lane >> 4;

  for (int h = 0; h < NH; ++h) {
    __syncthreads();   // prev head's Bsm reads done (and h=0: A staged)
    if (tid < 128) {
      int row = tid >> 1, ch = (tid & 1) * 64;
      const float* wr = W + (size_t)(h * CCH + row) * IN_DIM + ch;
#pragma unroll
      for (int i = 0; i < 64; i += 8) {
        float4 a = *(const float4*)(wr + i);
        float4 b = *(const float4*)(wr + i + 4);
        ushort4 u0, u1;
        u0.x = f2bf(a.x); u0.y = f2bf(a.y); u0.z = f2bf(a.z); u0.w = f2bf(a.w);
        u1.x = f2bf(b.x); u1.y = f2bf(b.y); u1.z = f2bf(b.z); u1.w = f2bf(b.w);
        *(ushort4*)&Bsm[row][ch + i]     = u0;
        *(ushort4*)&Bsm[row][ch + i + 4] = u1;
      }
    }
    __syncthreads();

    f32x4 acc[2][4] = {};
#pragma unroll
    for (int kk = 0; kk < 4; ++kk) {
      const int ko = kk * 32 + lk * 8;
      short8 af0 = *(const short8*)&Asm[wv * 32 + lr][ko];
      short8 af1 = *(const short8*)&Asm[wv * 32 + 16 + lr][ko];
      short8 bf0 = *(const short8*)&Bsm[lr][ko];
      short8 bf1 = *(const short8*)&Bsm[16 + lr][ko];
      short8 bf2v = *(const short8*)&Bsm[32 + lr][ko];
      short8 bf3 = *(const short8*)&Bsm[48 + lr][ko];
      acc[0][0] = __builtin_amdgcn_mfma_f32_16x16x32_bf16(af0, bf0, acc[0][0], 0, 0, 0);
      acc[0][1] = __builtin_amdgcn_mfma_f32_16x16x32_bf16(af0, bf1, acc[0][1], 0, 0, 0);
      acc[0][2] = __builtin_amdgcn_mfma_f32_16x16x32_bf16(af0, bf2v, acc[0][2], 0, 0, 0);
      acc[0][3] = __builtin_amdgcn_mfma_f32_16x16x32_bf16(af0, bf3, acc[0][3], 0, 0, 0);
      acc[1][0] = __builtin_amdgcn_mfma_f32_16x16x32_bf16(af1, bf0, acc[1][0], 0, 0, 0);
      acc[1][1] = __builtin_amdgcn_mfma_f32_16x16x32_bf16(af1, bf1, acc[1][1], 0, 0, 0);
      acc[1][2] = __builtin_amdgcn_mfma_f32_16x16x32_bf16(af1, bf2v, acc[1][2], 0, 0, 0);
      acc[1][3] = __builtin_amdgcn_mfma_f32_16x16x32_bf16(af1, bf3, acc[1][3], 0, 0, 0);
    }

    // epilogue head h
    float as4[4], ad4[4];
#pragma unroll
    for (int ni = 0; ni < 4; ++ni) {
      as4[ni] = att_src[h * CCH + ni * 16 + lr];
      ad4[ni] = att_dst[h * CCH + ni * 16 + lr];
    }
#pragma unroll
    for (int mi = 0; mi < 2; ++mi) {
#pragma unroll
      for (int r = 0; r < 4; ++r) {
        int gm = bm + wv * 32 + mi * 16 + lk * 4 + r;
        bool ok = (gm < Nn);
        if (ok) {
#pragma unroll
          for (int ni = 0; ni < 4; ++ni)
            xpb[(size_t)gm * HC + h * CCH + ni * 16 + lr] = f2bf(acc[mi][ni][r]);
        }
        float ps = 0.f, pd = 0.f;
#pragma unroll
        for (int ni = 0; ni < 4; ++ni) {
          ps += acc[mi][ni][r] * as4[ni];
          pd += acc[mi][ni][r] * ad4[ni];
        }
        ps += __shfl_xor(ps, 1); pd += __shfl_xor(pd, 1);
        ps += __shfl_xor(ps, 2); pd += __shfl_xor(pd, 2);
        ps += __shfl_xor(ps, 4); pd += __shfl_xor(pd, 4);
        ps += __shfl_xor(ps, 8); pd += __shfl_xor(pd, 8);
        if (lr == 0 && ok) {
          a_srcv[(size_t)gm * NH + h] = ps;
          a_dstv[(size_t)gm * NH + h] = pd;
        }
      }
    }
  }
}

// ---------------- K2: histogram of dst ----------------
__global__ void hist_k(const int* __restrict__ dst, int* __restrict__ counts, int E) {
  int e = blockIdx.x * 256 + threadIdx.x;
  if (e < E) atomicAdd(&counts[dst[e]], 1);
}

// ---------------- scan phase A: per-block (4096) reduce ----------------
__global__ void scanA_k(const int* __restrict__ counts, int* __restrict__ bsum, int n) {
  __shared__ int ts[256];
  int b = blockIdx.x, tid = threadIdx.x;
  int i0 = b * 4096 + tid * 16;
  int s = 0;
#pragma unroll
  for (int k = 0; k < 16; ++k) {
    int i = i0 + k;
    s += (i < n) ? counts[i] : 0;
  }
  ts[tid] = s;
  __syncthreads();
  for (int off = 128; off; off >>= 1) {
    if (tid < off) ts[tid] += ts[tid + off];
    __syncthreads();
  }
  if (tid == 0) bsum[b] = ts[0];
}

// ---------------- scan phase B: 1 wave scans <=64 block sums ----------------
__global__ void scanB_k(const int* __restrict__ bsum, int* __restrict__ bbase,
                        int nb, int* __restrict__ offsets, int n, int E) {
  int lane = threadIdx.x;
  int v = (lane < nb) ? bsum[lane] : 0;
  int orig = v;
#pragma unroll
  for (int off = 1; off < 64; off <<= 1) {
    int t = __shfl_up(v, off);
    if (lane >= off) v += t;
  }
  if (lane < nb) bbase[lane] = v - orig;
  if (lane == 0) offsets[n] = E;
}

// ---------------- scan phase C: rescan + write offsets & cursor ----------------
__global__ void scanC_k(const int* __restrict__ counts, const int* __restrict__ bbase,
                        int* __restrict__ offsets, int* __restrict__ cursor, int n) {
  __shared__ int ts[256];
  int b = blockIdx.x, tid = threadIdx.x;
  int i0 = b * 4096 + tid * 16;
  int pre[16];
  int s = 0;
#pragma unroll
  for (int k = 0; k < 16; ++k) {
    int i = i0 + k;
    pre[k] = s;
    s += (i < n) ? counts[i] : 0;
  }
  ts[tid] = s;
  __syncthreads();
  for (int off = 1; off < 256; off <<= 1) {
    int t = (tid >= off) ? ts[tid - off] : 0;
    __syncthreads();
    ts[tid] += t;
    __syncthreads();
  }
  int base = bbase[b] + (tid ? ts[tid - 1] : 0);
#pragma unroll
  for (int k = 0; k < 16; ++k) {
    int i = i0 + k;
    if (i < n) {
      int o = base + pre[k];
      offsets[i] = o;
      cursor[i] = o;
    }
  }
}

// ---------------- K4: scatter packed (etype<<26 | src) into dst-sorted order ----------------
__global__ void scatter_k(const int* __restrict__ src, const int* __restrict__ dst,
                          const int* __restrict__ et, int* __restrict__ cursor,
                          unsigned int* __restrict__ packed, int E) {
  int e = blockIdx.x * 256 + threadIdx.x;
  if (e >= E) return;
  int d = dst[e];
  unsigned int pk = ((unsigned int)et[e] << 26) | (unsigned int)src[e];
  int pos = atomicAdd(&cursor[d], 1);
  packed[pos] = pk;
}

// ---------------- K5: one wave per dst: recompute w, aggregate, write ----------------
__global__ void gat_out_k(const int* __restrict__ offsets,
                          const unsigned int* __restrict__ packed,
                          const float* __restrict__ a_srcv, const float* __restrict__ a_dstv,
                          const float* __restrict__ a_rel, int R,
                          const unsigned short* __restrict__ xpb,
                          const float* __restrict__ bias,
                          float* __restrict__ out, int Nn) {
  __shared__ float arl[NH * 64];
  int tid = threadIdx.x;
  if (tid < R * NH) arl[tid] = a_rel[tid];
  __syncthreads();
  int d = blockIdx.x * 4 + (tid >> 6);
  if (d >= Nn) return;
  int lane = tid & 63;
  int h = lane >> 4, c4 = (lane & 15) * 4;
  const int hco = h * CCH + c4;
  int beg = offsets[d], end = offsets[d + 1];
  float ad = a_dstv[(size_t)d * NH + h];
  float z = 0.f, a0 = 0.f, a1 = 0.f, a2 = 0.f, a3 = 0.f;
  int j = beg;
  for (; j + 4 <= end; j += 4) {
    unsigned int pk[4];
#pragma unroll
    for (int q = 0; q < 4; ++q) pk[q] = packed[j + q];
    float w[4]; ushort4 u[4];
#pragma unroll
    for (int q = 0; q < 4; ++q) {
      int s = (int)(pk[q] & 0x03FFFFFFu);
      int t = (int)(pk[q] >> 26);
      float al = a_srcv[(size_t)s * NH + h] + ad + arl[t * NH + h];
      al = fmaxf(al, NEG * al);
      w[q] = __expf(al);
      u[q] = *(const ushort4*)(xpb + (size_t)s * HC + hco);
    }
#pragma unroll
    for (int q = 0; q < 4; ++q) {
      z += w[q];
      a0 += w[q] * bf2f(u[q].x);
      a1 += w[q] * bf2f(u[q].y);
      a2 += w[q] * bf2f(u[q].z);
      a3 += w[q] * bf2f(u[q].w);
    }
  }
  for (; j < end; ++j) {
    unsigned int pk = packed[j];
    int s = (int)(pk & 0x03FFFFFFu);
    int t = (int)(pk >> 26);
    float al = a_srcv[(size_t)s * NH + h] + ad + arl[t * NH + h];
    al = fmaxf(al, NEG * al);
    float w = __expf(al);
    ushort4 u = *(const ushort4*)(xpb + (size_t)s * HC + hco);
    z += w;
    a0 += w * bf2f(u.x);
    a1 += w * bf2f(u.y);
    a2 += w * bf2f(u.z);
    a3 += w * bf2f(u.w);
  }
  float inv = 0.25f / (z + 1e-16f);
  a0 *= inv; a1 *= inv; a2 *= inv; a3 *= inv;
  a0 += __shfl_down(a0, 32); a1 += __shfl_down(a1, 32);
  a2 += __shfl_down(a2, 32); a3 += __shfl_down(a3, 32);
  a0 += __shfl_down(a0, 16); a1 += __shfl_down(a1, 16);
  a2 += __shfl_down(a2, 16); a3 += __shfl_down(a3, 16);
  if (lane < 16) {
    const float4 b4 = *(const float4*)(bias + lane * 4);
    float4 o;
    o.x = a0 + b4.x; o.y = a1 + b4.y; o.z = a2 + b4.z; o.w = a3 + b4.w;
    *(float4*)(out + (size_t)d * CCH + lane * 4) = o;
  }
}

extern "C" void kernel_launch(void* const* d_in, const int* in_sizes, int n_in,
                              void* d_out, int out_size, void* d_ws, size_t ws_size,
                              hipStream_t stream) {
  const float* x        = (const float*)d_in[0];
  const int*   eidx     = (const int*)d_in[1];
  const int*   etype    = (const int*)d_in[2];
  const float* rel_emb  = (const float*)d_in[3];
  const float* W        = (const float*)d_in[4];
  const float* att_src  = (const float*)d_in[5];
  const float* att_dst  = (const float*)d_in[6];
  const float* W_edge   = (const float*)d_in[7];
  const float* att_edge = (const float*)d_in[8];
  const float* bias     = (const float*)d_in[9];
  float* out = (float*)d_out;

  const int Nn = in_sizes[0] / IN_DIM;
  const int E  = in_sizes[1] / 2;
  const int R  = in_sizes[3] / IN_DIM;
  const int* src = eidx;
  const int* dst = eidx + E;

  char* ws = (char*)d_ws;
  size_t off = 0;
  auto alloc = [&](size_t bytes) {
    void* p = ws + off;
    off = (off + bytes + 255) & ~(size_t)255;
    return p;
  };
  unsigned short* xpb = (unsigned short*)alloc((size_t)Nn * HC * 2);
  float* a_srcv = (float*)alloc((size_t)Nn * NH * 4);
  float* a_dstv = (float*)alloc((size_t)Nn * NH * 4);
  float* a_rel  = (float*)alloc((size_t)R * NH * 4);
  int*   counts = (int*)alloc((size_t)Nn * 4);
  int*   offsets= (int*)alloc((size_t)(Nn + 1) * 4);
  int*   cursor = (int*)alloc((size_t)Nn * 4);
  int*   bsum   = (int*)alloc(256 * 4);
  int*   bbase  = (int*)alloc(256 * 4);
  unsigned int* packed = (unsigned int*)alloc((size_t)E * 4);

  const int NB = (Nn + 4095) / 4096;  // <= 64 required (Nn <= 262144)

  hipMemsetAsync(counts, 0, (size_t)Nn * 4, stream);

  hipLaunchKernelGGL(rel_attn_k, dim3(R), dim3(64), 0, stream,
                     rel_emb, W_edge, att_edge, a_rel);
  hipLaunchKernelGGL(gemm_mfma_k, dim3((Nn + 127) / 128), dim3(256), 0, stream,
                     x, W, att_src, att_dst, xpb, a_srcv, a_dstv, Nn);
  hipLaunchKernelGGL(hist_k, dim3((E + 255) / 256), dim3(256), 0, stream, dst, counts, E);
  hipLaunchKernelGGL(scanA_k, dim3(NB), dim3(256), 0, stream, counts, bsum, Nn);
  hipLaunchKernelGGL(scanB_k, dim3(1), dim3(64), 0, stream, bsum, bbase, NB, offsets, Nn, E);
  hipLaunchKernelGGL(scanC_k, dim3(NB), dim3(256), 0, stream, counts, bbase, offsets, cursor, Nn);
  hipLaunchKernelGGL(scatter_k, dim3((E + 255) / 256), dim3(256), 0, stream,
                     src, dst, etype, cursor, packed, E);
  hipLaunchKernelGGL(gat_out_k, dim3((Nn + 3) / 4), dim3(256), 0, stream,
                     offsets, packed, a_srcv, a_dstv, a_rel, R, xpb, bias, out, Nn);
}

// Round 6
// 213.983 us; speedup vs baseline: 1.4653x; 1.0272x over previous
//
#include <hip/hip_runtime.h>

#define IN_DIM 128
#define HC     256      // H*C
#define CCH    64
#define NH     4
#define NEG    0.2f

typedef __attribute__((ext_vector_type(4))) float f32x4;
typedef __attribute__((ext_vector_type(8))) short short8;

static __device__ __forceinline__ unsigned short f2bf(float f) {
  unsigned int u = __float_as_uint(f);
  u = (u + 0x7fffu + ((u >> 16) & 1u)) >> 16;   // RNE
  return (unsigned short)u;
}
static __device__ __forceinline__ float bf2f(unsigned short b) {
  return __uint_as_float(((unsigned int)b) << 16);
}

// ---------------- K0: per-relation attention term (factored) ----------------
// a_rel[r,h] = sum_k rel_emb[r,k] * v[h,k],  v[h,k] = sum_c att_edge[h,c]*W_edge[h*64+c,k]
// Single block, 512 threads. Phase 1: v into LDS (coalesced W_edge read, once).
// Phase 2: 256 threads compute the 256 outputs from LDS + L2-resident rel_emb.
__global__ __launch_bounds__(512) void rel_attn_k(
    const float* __restrict__ rel_emb, const float* __restrict__ W_edge,
    const float* __restrict__ att_edge, float* __restrict__ a_rel, int R) {
  __shared__ float v[NH * IN_DIM];  // 2 KB
  int tid = threadIdx.x;
  {
    int h = tid >> 7, k = tid & 127;
    const float* base = W_edge + (size_t)h * CCH * IN_DIM + k;
    const float* ae = att_edge + h * CCH;
    float s = 0.f;
#pragma unroll 8
    for (int c = 0; c < CCH; ++c) s += ae[c] * base[(size_t)c * IN_DIM];
    v[tid] = s;
  }
  __syncthreads();
  if (tid < R * NH) {
    int r = tid >> 2, h = tid & 3;
    const float4* re = (const float4*)(rel_emb + (size_t)r * IN_DIM);
    const float4* vv = (const float4*)(v + h * IN_DIM);
    float s = 0.f;
#pragma unroll 8
    for (int k = 0; k < IN_DIM / 4; ++k) {
      float4 a = re[k], b = vv[k];
      s += a.x * b.x + a.y * b.y + a.z * b.z + a.w * b.w;
    }
    a_rel[tid] = s;
  }
}

// ---------------- K1: MFMA bf16 GEMM, x staged ONCE, heads looped in-block ----------------
__global__ __launch_bounds__(256) void gemm_mfma_k(
    const float* __restrict__ x, const float* __restrict__ W,
    const float* __restrict__ att_src, const float* __restrict__ att_dst,
    unsigned short* __restrict__ xpb, float* __restrict__ a_srcv,
    float* __restrict__ a_dstv, int Nn) {
  __shared__ unsigned short Asm[128][136];  // 34.8 KB
  __shared__ unsigned short Bsm[64][136];   // 17.4 KB
  const int tid = threadIdx.x;
  const int bm = blockIdx.x * 128;

  // stage A (x rows bm..bm+127, f32 -> bf16), once
  {
    int row = tid >> 1, ch = (tid & 1) * 64;
    int gm = bm + row;
    if (gm < Nn) {
      const float* xr = x + (size_t)gm * IN_DIM + ch;
#pragma unroll
      for (int i = 0; i < 64; i += 8) {
        float4 a = *(const float4*)(xr + i);
        float4 b = *(const float4*)(xr + i + 4);
        ushort4 u0, u1;
        u0.x = f2bf(a.x); u0.y = f2bf(a.y); u0.z = f2bf(a.z); u0.w = f2bf(a.w);
        u1.x = f2bf(b.x); u1.y = f2bf(b.y); u1.z = f2bf(b.z); u1.w = f2bf(b.w);
        *(ushort4*)&Asm[row][ch + i]     = u0;
        *(ushort4*)&Asm[row][ch + i + 4] = u1;
      }
    } else {
      ushort4 zz = {0, 0, 0, 0};
#pragma unroll
      for (int i = 0; i < 64; i += 4) *(ushort4*)&Asm[row][ch + i] = zz;
    }
  }

  const int wv = tid >> 6, lane = tid & 63;
  const int lr = lane & 15, lk = lane >> 4;

  for (int h = 0; h < NH; ++h) {
    __syncthreads();   // prev head's Bsm reads done (and h=0: A staged)
    if (tid < 128) {
      int row = tid >> 1, ch = (tid & 1) * 64;
      const float* wr = W + (size_t)(h * CCH + row) * IN_DIM + ch;
#pragma unroll
      for (int i = 0; i < 64; i += 8) {
        float4 a = *(const float4*)(wr + i);
        float4 b = *(const float4*)(wr + i + 4);
        ushort4 u0, u1;
        u0.x = f2bf(a.x); u0.y = f2bf(a.y); u0.z = f2bf(a.z); u0.w = f2bf(a.w);
        u1.x = f2bf(b.x); u1.y = f2bf(b.y); u1.z = f2bf(b.z); u1.w = f2bf(b.w);
        *(ushort4*)&Bsm[row][ch + i]     = u0;
        *(ushort4*)&Bsm[row][ch + i + 4] = u1;
      }
    }
    __syncthreads();

    f32x4 acc[2][4] = {};
#pragma unroll
    for (int kk = 0; kk < 4; ++kk) {
      const int ko = kk * 32 + lk * 8;
      short8 af0 = *(const short8*)&Asm[wv * 32 + lr][ko];
      short8 af1 = *(const short8*)&Asm[wv * 32 + 16 + lr][ko];
      short8 bf0 = *(const short8*)&Bsm[lr][ko];
      short8 bf1 = *(const short8*)&Bsm[16 + lr][ko];
      short8 bf2v = *(const short8*)&Bsm[32 + lr][ko];
      short8 bf3 = *(const short8*)&Bsm[48 + lr][ko];
      acc[0][0] = __builtin_amdgcn_mfma_f32_16x16x32_bf16(af0, bf0, acc[0][0], 0, 0, 0);
      acc[0][1] = __builtin_amdgcn_mfma_f32_16x16x32_bf16(af0, bf1, acc[0][1], 0, 0, 0);
      acc[0][2] = __builtin_amdgcn_mfma_f32_16x16x32_bf16(af0, bf2v, acc[0][2], 0, 0, 0);
      acc[0][3] = __builtin_amdgcn_mfma_f32_16x16x32_bf16(af0, bf3, acc[0][3], 0, 0, 0);
      acc[1][0] = __builtin_amdgcn_mfma_f32_16x16x32_bf16(af1, bf0, acc[1][0], 0, 0, 0);
      acc[1][1] = __builtin_amdgcn_mfma_f32_16x16x32_bf16(af1, bf1, acc[1][1], 0, 0, 0);
      acc[1][2] = __builtin_amdgcn_mfma_f32_16x16x32_bf16(af1, bf2v, acc[1][2], 0, 0, 0);
      acc[1][3] = __builtin_amdgcn_mfma_f32_16x16x32_bf16(af1, bf3, acc[1][3], 0, 0, 0);
    }

    // epilogue head h
    float as4[4], ad4[4];
#pragma unroll
    for (int ni = 0; ni < 4; ++ni) {
      as4[ni] = att_src[h * CCH + ni * 16 + lr];
      ad4[ni] = att_dst[h * CCH + ni * 16 + lr];
    }
#pragma unroll
    for (int mi = 0; mi < 2; ++mi) {
#pragma unroll
      for (int r = 0; r < 4; ++r) {
        int gm = bm + wv * 32 + mi * 16 + lk * 4 + r;
        bool ok = (gm < Nn);
        if (ok) {
#pragma unroll
          for (int ni = 0; ni < 4; ++ni)
            xpb[(size_t)gm * HC + h * CCH + ni * 16 + lr] = f2bf(acc[mi][ni][r]);
        }
        float ps = 0.f, pd = 0.f;
#pragma unroll
        for (int ni = 0; ni < 4; ++ni) {
          ps += acc[mi][ni][r] * as4[ni];
          pd += acc[mi][ni][r] * ad4[ni];
        }
        ps += __shfl_xor(ps, 1); pd += __shfl_xor(pd, 1);
        ps += __shfl_xor(ps, 2); pd += __shfl_xor(pd, 2);
        ps += __shfl_xor(ps, 4); pd += __shfl_xor(pd, 4);
        ps += __shfl_xor(ps, 8); pd += __shfl_xor(pd, 8);
        if (lr == 0 && ok) {
          a_srcv[(size_t)gm * NH + h] = ps;
          a_dstv[(size_t)gm * NH + h] = pd;
        }
      }
    }
  }
}

// ---------------- K2: histogram of dst ----------------
__global__ void hist_k(const int* __restrict__ dst, int* __restrict__ counts, int E) {
  int e = blockIdx.x * 256 + threadIdx.x;
  if (e < E) atomicAdd(&counts[dst[e]], 1);
}

// ---------------- scan phase A: per-block (4096) reduce ----------------
__global__ void scanA_k(const int* __restrict__ counts, int* __restrict__ bsum, int n) {
  __shared__ int ts[256];
  int b = blockIdx.x, tid = threadIdx.x;
  int i0 = b * 4096 + tid * 16;
  int s = 0;
#pragma unroll
  for (int k = 0; k < 16; ++k) {
    int i = i0 + k;
    s += (i < n) ? counts[i] : 0;
  }
  ts[tid] = s;
  __syncthreads();
  for (int off = 128; off; off >>= 1) {
    if (tid < off) ts[tid] += ts[tid + off];
    __syncthreads();
  }
  if (tid == 0) bsum[b] = ts[0];
}

// ---------------- scan phase B: 1 wave scans <=64 block sums ----------------
__global__ void scanB_k(const int* __restrict__ bsum, int* __restrict__ bbase,
                        int nb, int* __restrict__ offsets, int n, int E) {
  int lane = threadIdx.x;
  int v = (lane < nb) ? bsum[lane] : 0;
  int orig = v;
#pragma unroll
  for (int off = 1; off < 64; off <<= 1) {
    int t = __shfl_up(v, off);
    if (lane >= off) v += t;
  }
  if (lane < nb) bbase[lane] = v - orig;
  if (lane == 0) offsets[n] = E;
}

// ---------------- scan phase C: rescan + write offsets & cursor ----------------
__global__ void scanC_k(const int* __restrict__ counts, const int* __restrict__ bbase,
                        int* __restrict__ offsets, int* __restrict__ cursor, int n) {
  __shared__ int ts[256];
  int b = blockIdx.x, tid = threadIdx.x;
  int i0 = b * 4096 + tid * 16;
  int pre[16];
  int s = 0;
#pragma unroll
  for (int k = 0; k < 16; ++k) {
    int i = i0 + k;
    pre[k] = s;
    s += (i < n) ? counts[i] : 0;
  }
  ts[tid] = s;
  __syncthreads();
  for (int off = 1; off < 256; off <<= 1) {
    int t = (tid >= off) ? ts[tid - off] : 0;
    __syncthreads();
    ts[tid] += t;
    __syncthreads();
  }
  int base = bbase[b] + (tid ? ts[tid - 1] : 0);
#pragma unroll
  for (int k = 0; k < 16; ++k) {
    int i = i0 + k;
    if (i < n) {
      int o = base + pre[k];
      offsets[i] = o;
      cursor[i] = o;
    }
  }
}

// ---------------- K4: scatter packed (etype<<26 | src) into dst-sorted order ----------------
__global__ void scatter_k(const int* __restrict__ src, const int* __restrict__ dst,
                          const int* __restrict__ et, int* __restrict__ cursor,
                          unsigned int* __restrict__ packed, int E) {
  int e = blockIdx.x * 256 + threadIdx.x;
  if (e >= E) return;
  int d = dst[e];
  unsigned int pk = ((unsigned int)et[e] << 26) | (unsigned int)src[e];
  int pos = atomicAdd(&cursor[d], 1);
  packed[pos] = pk;
}

// ---------------- K5: one wave per dst: recompute w, aggregate, write ----------------
__global__ void gat_out_k(const int* __restrict__ offsets,
                          const unsigned int* __restrict__ packed,
                          const float* __restrict__ a_srcv, const float* __restrict__ a_dstv,
                          const float* __restrict__ a_rel, int R,
                          const unsigned short* __restrict__ xpb,
                          const float* __restrict__ bias,
                          float* __restrict__ out, int Nn) {
  __shared__ float arl[NH * 64];
  int tid = threadIdx.x;
  if (tid < R * NH) arl[tid] = a_rel[tid];
  __syncthreads();
  int d = blockIdx.x * 4 + (tid >> 6);
  if (d >= Nn) return;
  int lane = tid & 63;
  int h = lane >> 4, c4 = (lane & 15) * 4;
  const int hco = h * CCH + c4;
  int beg = offsets[d], end = offsets[d + 1];
  float ad = a_dstv[(size_t)d * NH + h];
  float z = 0.f, a0 = 0.f, a1 = 0.f, a2 = 0.f, a3 = 0.f;
  int j = beg;
  for (; j + 8 <= end; j += 8) {
    unsigned int pk[8];
#pragma unroll
    for (int q = 0; q < 8; ++q) pk[q] = packed[j + q];
    float w[8]; ushort4 u[8];
#pragma unroll
    for (int q = 0; q < 8; ++q) {
      int s = (int)(pk[q] & 0x03FFFFFFu);
      int t = (int)(pk[q] >> 26);
      float al = a_srcv[(size_t)s * NH + h] + ad + arl[t * NH + h];
      al = fmaxf(al, NEG * al);
      w[q] = __expf(al);
      u[q] = *(const ushort4*)(xpb + (size_t)s * HC + hco);
    }
#pragma unroll
    for (int q = 0; q < 8; ++q) {
      z += w[q];
      a0 += w[q] * bf2f(u[q].x);
      a1 += w[q] * bf2f(u[q].y);
      a2 += w[q] * bf2f(u[q].z);
      a3 += w[q] * bf2f(u[q].w);
    }
  }
  for (; j < end; ++j) {
    unsigned int pk = packed[j];
    int s = (int)(pk & 0x03FFFFFFu);
    int t = (int)(pk >> 26);
    float al = a_srcv[(size_t)s * NH + h] + ad + arl[t * NH + h];
    al = fmaxf(al, NEG * al);
    float w = __expf(al);
    ushort4 u = *(const ushort4*)(xpb + (size_t)s * HC + hco);
    z += w;
    a0 += w * bf2f(u.x);
    a1 += w * bf2f(u.y);
    a2 += w * bf2f(u.z);
    a3 += w * bf2f(u.w);
  }
  float inv = 0.25f / (z + 1e-16f);
  a0 *= inv; a1 *= inv; a2 *= inv; a3 *= inv;
  a0 += __shfl_down(a0, 32); a1 += __shfl_down(a1, 32);
  a2 += __shfl_down(a2, 32); a3 += __shfl_down(a3, 32);
  a0 += __shfl_down(a0, 16); a1 += __shfl_down(a1, 16);
  a2 += __shfl_down(a2, 16); a3 += __shfl_down(a3, 16);
  if (lane < 16) {
    const float4 b4 = *(const float4*)(bias + lane * 4);
    float4 o;
    o.x = a0 + b4.x; o.y = a1 + b4.y; o.z = a2 + b4.z; o.w = a3 + b4.w;
    *(float4*)(out + (size_t)d * CCH + lane * 4) = o;
  }
}

extern "C" void kernel_launch(void* const* d_in, const int* in_sizes, int n_in,
                              void* d_out, int out_size, void* d_ws, size_t ws_size,
                              hipStream_t stream) {
  const float* x        = (const float*)d_in[0];
  const int*   eidx     = (const int*)d_in[1];
  const int*   etype    = (const int*)d_in[2];
  const float* rel_emb  = (const float*)d_in[3];
  const float* W        = (const float*)d_in[4];
  const float* att_src  = (const float*)d_in[5];
  const float* att_dst  = (const float*)d_in[6];
  const float* W_edge   = (const float*)d_in[7];
  const float* att_edge = (const float*)d_in[8];
  const float* bias     = (const float*)d_in[9];
  float* out = (float*)d_out;

  const int Nn = in_sizes[0] / IN_DIM;
  const int E  = in_sizes[1] / 2;
  const int R  = in_sizes[3] / IN_DIM;
  const int* src = eidx;
  const int* dst = eidx + E;

  char* ws = (char*)d_ws;
  size_t off = 0;
  auto alloc = [&](size_t bytes) {
    void* p = ws + off;
    off = (off + bytes + 255) & ~(size_t)255;
    return p;
  };
  unsigned short* xpb = (unsigned short*)alloc((size_t)Nn * HC * 2);
  float* a_srcv = (float*)alloc((size_t)Nn * NH * 4);
  float* a_dstv = (float*)alloc((size_t)Nn * NH * 4);
  float* a_rel  = (float*)alloc((size_t)R * NH * 4);
  int*   counts = (int*)alloc((size_t)Nn * 4);
  int*   offsets= (int*)alloc((size_t)(Nn + 1) * 4);
  int*   cursor = (int*)alloc((size_t)Nn * 4);
  int*   bsum   = (int*)alloc(256 * 4);
  int*   bbase  = (int*)alloc(256 * 4);
  unsigned int* packed = (unsigned int*)alloc((size_t)E * 4);

  const int NB = (Nn + 4095) / 4096;  // <= 64 required (Nn <= 262144)

  hipMemsetAsync(counts, 0, (size_t)Nn * 4, stream);

  hipLaunchKernelGGL(rel_attn_k, dim3(1), dim3(512), 0, stream,
                     rel_emb, W_edge, att_edge, a_rel, R);
  hipLaunchKernelGGL(gemm_mfma_k, dim3((Nn + 127) / 128), dim3(256), 0, stream,
                     x, W, att_src, att_dst, xpb, a_srcv, a_dstv, Nn);
  hipLaunchKernelGGL(hist_k, dim3((E + 255) / 256), dim3(256), 0, stream, dst, counts, E);
  hipLaunchKernelGGL(scanA_k, dim3(NB), dim3(256), 0, stream, counts, bsum, Nn);
  hipLaunchKernelGGL(scanB_k, dim3(1), dim3(64), 0, stream, bsum, bbase, NB, offsets, Nn, E);
  hipLaunchKernelGGL(scanC_k, dim3(NB), dim3(256), 0, stream, counts, bbase, offsets, cursor, Nn);
  hipLaunchKernelGGL(scatter_k, dim3((E + 255) / 256), dim3(256), 0, stream,
                     src, dst, etype, cursor, packed, E);
  hipLaunchKernelGGL(gat_out_k, dim3((Nn + 3) / 4), dim3(256), 0, stream,
                     offsets, packed, a_srcv, a_dstv, a_rel, R, xpb, bias, out, Nn);
}

// Round 7
// 181.536 us; speedup vs baseline: 1.7272x; 1.1787x over previous
//
#include <hip/hip_runtime.h>

#define IN_DIM 128
#define HC     256      // H*C
#define CCH    64
#define NH     4
#define NEG    0.2f

typedef __attribute__((ext_vector_type(4))) float f32x4;
typedef __attribute__((ext_vector_type(8))) short short8;

static __device__ __forceinline__ unsigned short f2bf(float f) {
  unsigned int u = __float_as_uint(f);
  u = (u + 0x7fffu + ((u >> 16) & 1u)) >> 16;   // RNE
  return (unsigned short)u;
}
static __device__ __forceinline__ float bf2f(unsigned short b) {
  return __uint_as_float(((unsigned int)b) << 16);
}

// ---------------- phase 1: fused rel_attn (block 0) + gemm (blocks 1..GB) + hist (rest) ----
__global__ __launch_bounds__(256) void phase1_k(
    const float* __restrict__ x, const float* __restrict__ W,
    const float* __restrict__ att_src, const float* __restrict__ att_dst,
    const float* __restrict__ rel_emb, const float* __restrict__ W_edge,
    const float* __restrict__ att_edge, const int* __restrict__ dst,
    unsigned short* __restrict__ xpb, float* __restrict__ a_srcv,
    float* __restrict__ a_dstv, float* __restrict__ a_rel,
    int* __restrict__ counts, int Nn, int E, int R, int GB, int HB) {
  __shared__ unsigned short Asm[128][136];  // 34.8 KB
  __shared__ unsigned short Bsm[64][136];   // 17.4 KB
  const int bid = blockIdx.x;
  const int tid = threadIdx.x;

  if (bid == 0) {
    // ----- rel_attn: a_rel[r,h] = rel_emb[r,:] . v[h,:],  v[h,k]=sum_c ae[h,c]*W_edge[h*64+c,k]
    float* v = (float*)&Asm[0][0];  // 512 floats
    for (int t = tid; t < NH * IN_DIM; t += 256) {
      int h = t >> 7, k = t & 127;
      const float* base = W_edge + (size_t)h * CCH * IN_DIM + k;
      const float* ae = att_edge + h * CCH;
      float s = 0.f;
#pragma unroll 8
      for (int c = 0; c < CCH; ++c) s += ae[c] * base[(size_t)c * IN_DIM];
      v[t] = s;
    }
    __syncthreads();
    if (tid < R * NH) {
      int r = tid >> 2, h = tid & 3;
      const float4* re = (const float4*)(rel_emb + (size_t)r * IN_DIM);
      const float4* vv = (const float4*)(v + h * IN_DIM);
      float s = 0.f;
#pragma unroll 8
      for (int k = 0; k < IN_DIM / 4; ++k) {
        float4 a = re[k], b = vv[k];
        s += a.x * b.x + a.y * b.y + a.z * b.z + a.w * b.w;
      }
      a_rel[tid] = s;
    }
    return;
  }

  if (bid > GB) {
    // ----- hist: grid-stride histogram of dst
    for (int e = (bid - GB - 1) * 256 + tid; e < E; e += HB * 256)
      atomicAdd(&counts[dst[e]], 1);
    return;
  }

  // ----- gemm: BM=128 rows, heads looped in-block
  const int bm = (bid - 1) * 128;
  {
    int row = tid >> 1, ch = (tid & 1) * 64;
    int gm = bm + row;
    if (gm < Nn) {
      const float* xr = x + (size_t)gm * IN_DIM + ch;
#pragma unroll
      for (int i = 0; i < 64; i += 8) {
        float4 a = *(const float4*)(xr + i);
        float4 b = *(const float4*)(xr + i + 4);
        ushort4 u0, u1;
        u0.x = f2bf(a.x); u0.y = f2bf(a.y); u0.z = f2bf(a.z); u0.w = f2bf(a.w);
        u1.x = f2bf(b.x); u1.y = f2bf(b.y); u1.z = f2bf(b.z); u1.w = f2bf(b.w);
        *(ushort4*)&Asm[row][ch + i]     = u0;
        *(ushort4*)&Asm[row][ch + i + 4] = u1;
      }
    } else {
      ushort4 zz = {0, 0, 0, 0};
#pragma unroll
      for (int i = 0; i < 64; i += 4) *(ushort4*)&Asm[row][ch + i] = zz;
    }
  }

  const int wv = tid >> 6, lane = tid & 63;
  const int lr = lane & 15, lk = lane >> 4;

  for (int h = 0; h < NH; ++h) {
    __syncthreads();   // prev head's Bsm reads done (and h=0: A staged)
    if (tid < 128) {
      int row = tid >> 1, ch = (tid & 1) * 64;
      const float* wr = W + (size_t)(h * CCH + row) * IN_DIM + ch;
#pragma unroll
      for (int i = 0; i < 64; i += 8) {
        float4 a = *(const float4*)(wr + i);
        float4 b = *(const float4*)(wr + i + 4);
        ushort4 u0, u1;
        u0.x = f2bf(a.x); u0.y = f2bf(a.y); u0.z = f2bf(a.z); u0.w = f2bf(a.w);
        u1.x = f2bf(b.x); u1.y = f2bf(b.y); u1.z = f2bf(b.z); u1.w = f2bf(b.w);
        *(ushort4*)&Bsm[row][ch + i]     = u0;
        *(ushort4*)&Bsm[row][ch + i + 4] = u1;
      }
    }
    __syncthreads();

    f32x4 acc[2][4] = {};
#pragma unroll
    for (int kk = 0; kk < 4; ++kk) {
      const int ko = kk * 32 + lk * 8;
      short8 af0 = *(const short8*)&Asm[wv * 32 + lr][ko];
      short8 af1 = *(const short8*)&Asm[wv * 32 + 16 + lr][ko];
      short8 bf0 = *(const short8*)&Bsm[lr][ko];
      short8 bf1 = *(const short8*)&Bsm[16 + lr][ko];
      short8 bf2v = *(const short8*)&Bsm[32 + lr][ko];
      short8 bf3 = *(const short8*)&Bsm[48 + lr][ko];
      acc[0][0] = __builtin_amdgcn_mfma_f32_16x16x32_bf16(af0, bf0, acc[0][0], 0, 0, 0);
      acc[0][1] = __builtin_amdgcn_mfma_f32_16x16x32_bf16(af0, bf1, acc[0][1], 0, 0, 0);
      acc[0][2] = __builtin_amdgcn_mfma_f32_16x16x32_bf16(af0, bf2v, acc[0][2], 0, 0, 0);
      acc[0][3] = __builtin_amdgcn_mfma_f32_16x16x32_bf16(af0, bf3, acc[0][3], 0, 0, 0);
      acc[1][0] = __builtin_amdgcn_mfma_f32_16x16x32_bf16(af1, bf0, acc[1][0], 0, 0, 0);
      acc[1][1] = __builtin_amdgcn_mfma_f32_16x16x32_bf16(af1, bf1, acc[1][1], 0, 0, 0);
      acc[1][2] = __builtin_amdgcn_mfma_f32_16x16x32_bf16(af1, bf2v, acc[1][2], 0, 0, 0);
      acc[1][3] = __builtin_amdgcn_mfma_f32_16x16x32_bf16(af1, bf3, acc[1][3], 0, 0, 0);
    }

    // epilogue head h
    float as4[4], ad4[4];
#pragma unroll
    for (int ni = 0; ni < 4; ++ni) {
      as4[ni] = att_src[h * CCH + ni * 16 + lr];
      ad4[ni] = att_dst[h * CCH + ni * 16 + lr];
    }
#pragma unroll
    for (int mi = 0; mi < 2; ++mi) {
#pragma unroll
      for (int r = 0; r < 4; ++r) {
        int gm = bm + wv * 32 + mi * 16 + lk * 4 + r;
        bool ok = (gm < Nn);
        if (ok) {
#pragma unroll
          for (int ni = 0; ni < 4; ++ni)
            xpb[(size_t)gm * HC + h * CCH + ni * 16 + lr] = f2bf(acc[mi][ni][r]);
        }
        float ps = 0.f, pd = 0.f;
#pragma unroll
        for (int ni = 0; ni < 4; ++ni) {
          ps += acc[mi][ni][r] * as4[ni];
          pd += acc[mi][ni][r] * ad4[ni];
        }
        ps += __shfl_xor(ps, 1); pd += __shfl_xor(pd, 1);
        ps += __shfl_xor(ps, 2); pd += __shfl_xor(pd, 2);
        ps += __shfl_xor(ps, 4); pd += __shfl_xor(pd, 4);
        ps += __shfl_xor(ps, 8); pd += __shfl_xor(pd, 8);
        if (lr == 0 && ok) {
          a_srcv[(size_t)gm * NH + h] = ps;
          a_dstv[(size_t)gm * NH + h] = pd;
        }
      }
    }
  }
}

// ---------------- scan phase A: per-block (4096) reduce ----------------
__global__ void scanA_k(const int* __restrict__ counts, int* __restrict__ bsum, int n) {
  __shared__ int ts[256];
  int b = blockIdx.x, tid = threadIdx.x;
  int i0 = b * 4096 + tid * 16;
  int s = 0;
#pragma unroll
  for (int k = 0; k < 16; ++k) {
    int i = i0 + k;
    s += (i < n) ? counts[i] : 0;
  }
  ts[tid] = s;
  __syncthreads();
  for (int off = 128; off; off >>= 1) {
    if (tid < off) ts[tid] += ts[tid + off];
    __syncthreads();
  }
  if (tid == 0) bsum[b] = ts[0];
}

// ---------------- scan phase B: 1 wave scans <=64 block sums ----------------
__global__ void scanB_k(const int* __restrict__ bsum, int* __restrict__ bbase,
                        int nb, int* __restrict__ offsets, int n, int E) {
  int lane = threadIdx.x;
  int v = (lane < nb) ? bsum[lane] : 0;
  int orig = v;
#pragma unroll
  for (int off = 1; off < 64; off <<= 1) {
    int t = __shfl_up(v, off);
    if (lane >= off) v += t;
  }
  if (lane < nb) bbase[lane] = v - orig;
  if (lane == 0) offsets[n] = E;
}

// ---------------- scan phase C: rescan + write offsets & cursor ----------------
__global__ void scanC_k(const int* __restrict__ counts, const int* __restrict__ bbase,
                        int* __restrict__ offsets, int* __restrict__ cursor, int n) {
  __shared__ int ts[256];
  int b = blockIdx.x, tid = threadIdx.x;
  int i0 = b * 4096 + tid * 16;
  int pre[16];
  int s = 0;
#pragma unroll
  for (int k = 0; k < 16; ++k) {
    int i = i0 + k;
    pre[k] = s;
    s += (i < n) ? counts[i] : 0;
  }
  ts[tid] = s;
  __syncthreads();
  for (int off = 1; off < 256; off <<= 1) {
    int t = (tid >= off) ? ts[tid - off] : 0;
    __syncthreads();
    ts[tid] += t;
    __syncthreads();
  }
  int base = bbase[b] + (tid ? ts[tid - 1] : 0);
#pragma unroll
  for (int k = 0; k < 16; ++k) {
    int i = i0 + k;
    if (i < n) {
      int o = base + pre[k];
      offsets[i] = o;
      cursor[i] = o;
    }
  }
}

// ---------------- K4: scatter packed (etype<<26 | src) into dst-sorted order ----------------
__global__ void scatter_k(const int* __restrict__ src, const int* __restrict__ dst,
                          const int* __restrict__ et, int* __restrict__ cursor,
                          unsigned int* __restrict__ packed, int E) {
  int e = blockIdx.x * 256 + threadIdx.x;
  if (e >= E) return;
  int d = dst[e];
  unsigned int pk = ((unsigned int)et[e] << 26) | (unsigned int)src[e];
  int pos = atomicAdd(&cursor[d], 1);
  packed[pos] = pk;
}

// ---------------- K5: one wave per dst: recompute w, aggregate, write ----------------
__global__ void gat_out_k(const int* __restrict__ offsets,
                          const unsigned int* __restrict__ packed,
                          const float* __restrict__ a_srcv, const float* __restrict__ a_dstv,
                          const float* __restrict__ a_rel, int R,
                          const unsigned short* __restrict__ xpb,
                          const float* __restrict__ bias,
                          float* __restrict__ out, int Nn) {
  __shared__ float arl[NH * 64];
  int tid = threadIdx.x;
  if (tid < R * NH) arl[tid] = a_rel[tid];
  __syncthreads();
  int d = blockIdx.x * 4 + (tid >> 6);
  if (d >= Nn) return;
  int lane = tid & 63;
  int h = lane >> 4, c4 = (lane & 15) * 4;
  const int hco = h * CCH + c4;
  int beg = offsets[d], end = offsets[d + 1];
  float ad = a_dstv[(size_t)d * NH + h];
  float z = 0.f, a0 = 0.f, a1 = 0.f, a2 = 0.f, a3 = 0.f;
  int j = beg;
  for (; j + 4 <= end; j += 4) {
    unsigned int pk[4];
#pragma unroll
    for (int q = 0; q < 4; ++q) pk[q] = packed[j + q];
    float w[4]; ushort4 u[4];
#pragma unroll
    for (int q = 0; q < 4; ++q) {
      int s = (int)(pk[q] & 0x03FFFFFFu);
      int t = (int)(pk[q] >> 26);
      float al = a_srcv[(size_t)s * NH + h] + ad + arl[t * NH + h];
      al = fmaxf(al, NEG * al);
      w[q] = __expf(al);
      u[q] = *(const ushort4*)(xpb + (size_t)s * HC + hco);
    }
#pragma unroll
    for (int q = 0; q < 4; ++q) {
      z += w[q];
      a0 += w[q] * bf2f(u[q].x);
      a1 += w[q] * bf2f(u[q].y);
      a2 += w[q] * bf2f(u[q].z);
      a3 += w[q] * bf2f(u[q].w);
    }
  }
  for (; j < end; ++j) {
    unsigned int pk = packed[j];
    int s = (int)(pk & 0x03FFFFFFu);
    int t = (int)(pk >> 26);
    float al = a_srcv[(size_t)s * NH + h] + ad + arl[t * NH + h];
    al = fmaxf(al, NEG * al);
    float w = __expf(al);
    ushort4 u = *(const ushort4*)(xpb + (size_t)s * HC + hco);
    z += w;
    a0 += w * bf2f(u.x);
    a1 += w * bf2f(u.y);
    a2 += w * bf2f(u.z);
    a3 += w * bf2f(u.w);
  }
  float inv = 0.25f / (z + 1e-16f);
  a0 *= inv; a1 *= inv; a2 *= inv; a3 *= inv;
  a0 += __shfl_down(a0, 32); a1 += __shfl_down(a1, 32);
  a2 += __shfl_down(a2, 32); a3 += __shfl_down(a3, 32);
  a0 += __shfl_down(a0, 16); a1 += __shfl_down(a1, 16);
  a2 += __shfl_down(a2, 16); a3 += __shfl_down(a3, 16);
  if (lane < 16) {
    const float4 b4 = *(const float4*)(bias + lane * 4);
    float4 o;
    o.x = a0 + b4.x; o.y = a1 + b4.y; o.z = a2 + b4.z; o.w = a3 + b4.w;
    *(float4*)(out + (size_t)d * CCH + lane * 4) = o;
  }
}

extern "C" void kernel_launch(void* const* d_in, const int* in_sizes, int n_in,
                              void* d_out, int out_size, void* d_ws, size_t ws_size,
                              hipStream_t stream) {
  const float* x        = (const float*)d_in[0];
  const int*   eidx     = (const int*)d_in[1];
  const int*   etype    = (const int*)d_in[2];
  const float* rel_emb  = (const float*)d_in[3];
  const float* W        = (const float*)d_in[4];
  const float* att_src  = (const float*)d_in[5];
  const float* att_dst  = (const float*)d_in[6];
  const float* W_edge   = (const float*)d_in[7];
  const float* att_edge = (const float*)d_in[8];
  const float* bias     = (const float*)d_in[9];
  float* out = (float*)d_out;

  const int Nn = in_sizes[0] / IN_DIM;
  const int E  = in_sizes[1] / 2;
  const int R  = in_sizes[3] / IN_DIM;
  const int* src = eidx;
  const int* dst = eidx + E;

  char* ws = (char*)d_ws;
  size_t off = 0;
  auto alloc = [&](size_t bytes) {
    void* p = ws + off;
    off = (off + bytes + 255) & ~(size_t)255;
    return p;
  };
  unsigned short* xpb = (unsigned short*)alloc((size_t)Nn * HC * 2);
  float* a_srcv = (float*)alloc((size_t)Nn * NH * 4);
  float* a_dstv = (float*)alloc((size_t)Nn * NH * 4);
  float* a_rel  = (float*)alloc((size_t)R * NH * 4);
  int*   counts = (int*)alloc((size_t)Nn * 4);
  int*   offsets= (int*)alloc((size_t)(Nn + 1) * 4);
  int*   cursor = (int*)alloc((size_t)Nn * 4);
  int*   bsum   = (int*)alloc(256 * 4);
  int*   bbase  = (int*)alloc(256 * 4);
  unsigned int* packed = (unsigned int*)alloc((size_t)E * 4);

  const int NB = (Nn + 4095) / 4096;  // <= 64 required (Nn <= 262144)
  const int GB = (Nn + 127) / 128;    // gemm blocks
  const int HB = 512;                 // hist blocks

  hipMemsetAsync(counts, 0, (size_t)Nn * 4, stream);

  hipLaunchKernelGGL(phase1_k, dim3(1 + GB + HB), dim3(256), 0, stream,
                     x, W, att_src, att_dst, rel_emb, W_edge, att_edge, dst,
                     xpb, a_srcv, a_dstv, a_rel, counts, Nn, E, R, GB, HB);
  hipLaunchKernelGGL(scanA_k, dim3(NB), dim3(256), 0, stream, counts, bsum, Nn);
  hipLaunchKernelGGL(scanB_k, dim3(1), dim3(64), 0, stream, bsum, bbase, NB, offsets, Nn, E);
  hipLaunchKernelGGL(scanC_k, dim3(NB), dim3(256), 0, stream, counts, bbase, offsets, cursor, Nn);
  hipLaunchKernelGGL(scatter_k, dim3((E + 255) / 256), dim3(256), 0, stream,
                     src, dst, etype, cursor, packed, E);
  hipLaunchKernelGGL(gat_out_k, dim3((Nn + 3) / 4), dim3(256), 0, stream,
                     offsets, packed, a_srcv, a_dstv, a_rel, R, xpb, bias, out, Nn);
}